// Round 6
// baseline (252.467 us; speedup 1.0000x reference)
//
#include <hip/hip_runtime.h>
#include <cstdint>
#include <cstddef>

// PointerNetwork: B=256, S=512, H=128, CHAR/CLASS=10, OUT=64, WE=32
// R7 design (256-thread / 1-wave-per-SIMD MFMA recurrence):
//  - R6's M=1 MFMA scheme, re-partitioned: 4 waves, wave w owns units
//    32w..32w+31; lane<16 handles 2 units (h=0/1 subtiles) x 4 gates = 8
//    acc tiles. 96 MFMA/wave/step (same per-SIMD issue as R6's 8x48).
//  - KEY: per-thread weights = 96 x uint4 = 384 regs now FIT the register
//    file: 1 wave/SIMD (launch_bounds(256,1)) -> 512 unified regs/wave.
//    R6's 512-thread layout needed 320 > 256 budget -> compiler pushed
//    weight loads into the loop (the measured ~2000 cyc/step fixed cost).
//    "+a" asm pins them in AGPRs; MFMA reads B from AGPR natively.
//  - superphase (1 barrier/step), LDS h-history + fused epilogue as R5/R6.

#define HIST 128
#define HPAD 132

typedef _Float16 f16x8 __attribute__((ext_vector_type(8)));
typedef float    f32x4 __attribute__((ext_vector_type(4)));

__device__ __forceinline__ f16x8 as_h8(const uint4& v) {
    f16x8 r; __builtin_memcpy(&r, &v, 16); return r;
}

#define MFMA16(a, b, c) __builtin_amdgcn_mfma_f32_16x16x32_f16((a), (b), (c), 0, 0, 0)

__device__ __forceinline__ float fast_rcp(float x) {
#if __has_builtin(__builtin_amdgcn_rcpf)
    return __builtin_amdgcn_rcpf(x);
#else
    return 1.f / x;
#endif
}
__device__ __forceinline__ float sigm(float x) {
    x = fminf(fmaxf(x, -30.f), 30.f);
    return fast_rcp(1.f + __expf(-x));
}
__device__ __forceinline__ float tanh_fast(float x) {
    x = fminf(fmaxf(x, -15.f), 15.f);
    float e = __expf(-2.f * x);
    return (1.f - e) * fast_rcp(1.f + e);
}

// ---------------- P0: merged prep: XW1 table + MFMA B-frag packing -----------
// blocks 0..9: XW1 row for word id = blk.  blocks 10..57: pack WF.
// k_lstm thread thr = (w=thr>>6, l=thr&63):
//  f 0..63  L2: j=f>>4, h=(f>>3)&1, ks=f&7   (K=256: k<128 l2_Wh, else l2_Wx)
//  f 64..95 L1: f2=f-64: j=f2>>3, h=(f2>>2)&1, ks=f2&3  (l1_Wh)
// col = j*128 + 32*w + 16*h + (l&15); elems e: k = ks*32 + 8*(l>>4) + e.
__global__ __launch_bounds__(512) void k_prep(
    const float* __restrict__ emb_char, const float* __restrict__ emb_word,
    const float* __restrict__ Wwc, const float* __restrict__ bwc,
    const float* __restrict__ l1_Wx, const float* __restrict__ l1_b,
    const float* __restrict__ l1_Wh, const float* __restrict__ l2_Wx,
    const float* __restrict__ l2_Wh,
    float* __restrict__ XW1, uint4* __restrict__ WF)
{
    const int blk = blockIdx.x;
    const int T = threadIdx.x;
    if (blk < 10) {
        __shared__ float xw[64];
        if (T < 64) {
            float acc = emb_char[T] + bwc[T];   // emb_char row 0 (active steps have char==0)
            for (int m = 0; m < 32; ++m) acc += emb_word[blk * 32 + m] * Wwc[m * 64 + T];
            xw[T] = acc;
        }
        __syncthreads();
        float acc = l1_b[T];
        for (int k = 0; k < 64; ++k) acc += xw[k] * l1_Wx[k * 512 + T];
        XW1[blk * 512 + T] = acc;
    } else {
        const int gid = (blk - 10) * 512 + T;   // 0..24575 frags
        const int thr = gid / 96;
        const int f   = gid - thr * 96;
        const int w   = thr >> 6, l = thr & 63;
        const int kb  = 8 * (l >> 4);
        const bool isL2 = (f < 96 - 32);
        int j, h, ks;
        if (isL2) { j = f >> 4; h = (f >> 3) & 1; ks = f & 7; }
        else      { const int f2 = f - 64; j = f2 >> 3; h = (f2 >> 2) & 1; ks = f2 & 3; }
        const int col = j * 128 + 32 * w + 16 * h + (l & 15);
        union { uint4 qv; _Float16 hh[8]; } o;
        for (int e = 0; e < 8; ++e) {
            const int k = ks * 32 + kb + e;
            float v;
            if (isL2) v = (k < 128) ? l2_Wh[k * 512 + col] : l2_Wx[(k - 128) * 512 + col];
            else      v = l1_Wh[k * 512 + col];
            o.hh[e] = (_Float16)v;
        }
        WF[gid] = o.qv;   // gid == thr*96 + f
    }
}

// ---------------- main kernel: MFMA recurrence + fused epilogue --------------
__global__ __launch_bounds__(256, 1) void k_lstm(
    const int* __restrict__ char_ids, const int* __restrict__ word_ids,
    const int* __restrict__ subject_ids,
    const float* __restrict__ XW1, const uint4* __restrict__ WF,
    const float* __restrict__ l2_b,
    const float* __restrict__ beta_W, const float* __restrict__ beta_b,
    const float* __restrict__ gamma_W, const float* __restrict__ gamma_b,
    const float* __restrict__ sub_W, const float* __restrict__ sub_b,
    const float* __restrict__ po_W, const float* __restrict__ po_b,
    float* __restrict__ out)
{
    const int b    = blockIdx.x;
    const int T    = threadIdx.x;   // 0..255
    const int lane = T & 63;
    const int wv   = T >> 6;        // wave 0..3
    const int l15  = lane & 15;
    const int kb   = 8 * (lane >> 4);      // k-slab base within 32
    const bool g16 = (lane < 16);
    const int u0   = 32 * wv + l15;        // this lane's unit, h=0 subtile
    const int u1   = u0 + 16;              // h=1 subtile

    __shared__ int   charL[512];
    __shared__ int   wordL[512];
    __shared__ float XW1L[5120];                        // 10x512 XW1 table
    __shared__ __align__(16) _Float16 hcat[2][256];     // [h2 | h1n] dbuf
    __shared__ short wlist[512];
    __shared__ unsigned short idxL[512];
    __shared__ int   ccnt[8];
    __shared__ __align__(16) float hl[HIST * HPAD];     // h-history (f32)
    // epilogue workspace
    __shared__ float A[20][132];
    __shared__ float K1[20], K2[20];
    __shared__ float gm[128], bt[128];
    __shared__ float urs[HIST][2];
    __shared__ float povals[HIST * 20];
    __shared__ float subv[HIST * 2];
    __shared__ float swl[256];
    __shared__ float subj[256];

    charL[T]       = char_ids[b * 512 + T];
    charL[256 + T] = char_ids[b * 512 + 256 + T];
    wordL[T]       = word_ids[b * 512 + T];
    wordL[256 + T] = word_ids[b * 512 + 256 + T];
    for (int i = T; i < 5120; i += 256) XW1L[i] = XW1[i];
    __syncthreads();

    // compact active-step list (ordered): pass0 = steps 0..255 (chunks 0..3),
    // pass1 = steps 256..511 (chunks 4..7)
    const bool act0 = (charL[T] == 0);
    const bool act1 = (charL[256 + T] == 0);
    const unsigned long long bm0 = __ballot(act0);
    const unsigned long long bm1 = __ballot(act1);
    if (lane == 0) { ccnt[wv] = (int)__popcll(bm0); ccnt[4 + wv] = (int)__popcll(bm1); }
    __syncthreads();
    int baseC[8];
    int tot = 0;
    for (int i = 0; i < 8; ++i) { baseC[i] = tot; tot += ccnt[i]; }
    const int nact = tot;
    if (act0) wlist[baseC[wv]     + (int)__popcll(bm0 & ((1ull << lane) - 1ull))] = (short)wordL[T];
    if (act1) wlist[baseC[4 + wv] + (int)__popcll(bm1 & ((1ull << lane) - 1ull))] = (short)wordL[256 + T];
    {
        const int c0 = baseC[wv]     + (int)__popcll(bm0 & ((2ull << lane) - 1ull));
        const int c1 = baseC[4 + wv] + (int)__popcll(bm1 & ((2ull << lane) - 1ull));
        idxL[T]       = (unsigned short)(c0 < HIST - 1 ? c0 : HIST - 1);
        idxL[256 + T] = (unsigned short)(c1 < HIST - 1 ? c1 : HIST - 1);
    }

    // init state
    if (T < 128) {
        hcat[0][T] = (_Float16)0.f;   // h2(-1) = 0
        hl[T]      = 0.f;             // slot 0 = zeros
    }
    float c1_0 = 0.f, c1_1 = 0.f, c2_0 = 0.f, c2_1 = 0.f;   // valid on lanes<16
    const float l2b00 = l2_b[u0],       l2b01 = l2_b[u1];
    const float l2b10 = l2_b[128 + u0], l2b11 = l2_b[128 + u1];
    const float l2b20 = l2_b[256 + u0], l2b21 = l2_b[256 + u1];
    const float l2b30 = l2_b[384 + u0], l2b31 = l2_b[384 + u1];

    // persistent MFMA B-fragments: 96 x uint4 = 384 regs, pinned in AGPRs
    uint4 wf[96];
    {
        const uint4* p = WF + (size_t)T * 96;
#pragma unroll
        for (int i = 0; i < 96; ++i) wf[i] = p[i];
    }
#pragma unroll
    for (int i = 0; i < 96; ++i)
        asm volatile("" : "+a"(wf[i].x), "+a"(wf[i].y), "+a"(wf[i].z), "+a"(wf[i].w));
    __syncthreads();

    // prologue: L1 gates for step 0 (h1 == 0 -> z = xw)
    if (nact > 0) {
        const int w0_ = wlist[0];
        const float zi0 = XW1L[w0_ * 512 + u0],       zi1 = XW1L[w0_ * 512 + u1];
        const float zg0 = XW1L[w0_ * 512 + 256 + u0], zg1 = XW1L[w0_ * 512 + 256 + u1];
        const float zo0 = XW1L[w0_ * 512 + 384 + u0], zo1 = XW1L[w0_ * 512 + 384 + u1];
        c1_0 = sigm(zi0) * tanh_fast(zg0);            // c1_old == 0
        c1_1 = sigm(zi1) * tanh_fast(zg1);
        const float h1n0 = sigm(zo0) * tanh_fast(c1_0);
        const float h1n1 = sigm(zo1) * tanh_fast(c1_1);
        if (g16) {
            hcat[0][128 + u0] = (_Float16)h1n0;
            hcat[0][128 + u1] = (_Float16)h1n1;
        }
        __syncthreads();
    }

    // superphase a: hcat[cur] = [h2(a-1) | h1n(a)].
    int cur = 0;
    for (int a = 0; a < nact; ++a) {
        const _Float16* hc = hcat[cur];
        _Float16*       hn = hcat[cur ^ 1];

        // ---- L2: 8 acc tiles (4 gates x 2 unit-halves), K=256 ----
        f32x4 q00 = {l2b00, 0.f, 0.f, 0.f}, q01 = {l2b01, 0.f, 0.f, 0.f};
        f32x4 q10 = {l2b10, 0.f, 0.f, 0.f}, q11 = {l2b11, 0.f, 0.f, 0.f};
        f32x4 q20 = {l2b20, 0.f, 0.f, 0.f}, q21 = {l2b21, 0.f, 0.f, 0.f};
        f32x4 q30 = {l2b30, 0.f, 0.f, 0.f}, q31 = {l2b31, 0.f, 0.f, 0.f};
#pragma unroll
        for (int ks = 0; ks < 8; ++ks) {
            const f16x8 aa = *(const f16x8*)&hc[kb + 32 * ks];
            q00 = MFMA16(aa, as_h8(wf[ 0 + ks]), q00);
            q01 = MFMA16(aa, as_h8(wf[ 8 + ks]), q01);
            q10 = MFMA16(aa, as_h8(wf[16 + ks]), q10);
            q11 = MFMA16(aa, as_h8(wf[24 + ks]), q11);
            q20 = MFMA16(aa, as_h8(wf[32 + ks]), q20);
            q21 = MFMA16(aa, as_h8(wf[40 + ks]), q21);
            q30 = MFMA16(aa, as_h8(wf[48 + ks]), q30);
            q31 = MFMA16(aa, as_h8(wf[56 + ks]), q31);
        }
        if (g16) {
            c2_0 = sigm(q10[0]) * c2_0 + sigm(q00[0]) * tanh_fast(q20[0]);
            const float h2v0 = sigm(q30[0]) * tanh_fast(c2_0);
            c2_1 = sigm(q11[0]) * c2_1 + sigm(q01[0]) * tanh_fast(q21[0]);
            const float h2v1 = sigm(q31[0]) * tanh_fast(c2_1);
            hn[u0] = (_Float16)h2v0;
            hn[u1] = (_Float16)h2v1;
            const int slot = (a + 1 < HIST - 1) ? a + 1 : HIST - 1;
            hl[slot * HPAD + u0] = h2v0;
            hl[slot * HPAD + u1] = h2v1;
        }

        // ---- L1 for step a+1: K=128 over h1n(a) ----
        if (a + 1 < nact) {
            const int wid = wlist[a + 1];
            const float* xb = &XW1L[wid * 512];
            f32x4 r00 = {xb[u0],       0.f, 0.f, 0.f}, r01 = {xb[u1],       0.f, 0.f, 0.f};
            f32x4 r10 = {xb[128 + u0], 0.f, 0.f, 0.f}, r11 = {xb[128 + u1], 0.f, 0.f, 0.f};
            f32x4 r20 = {xb[256 + u0], 0.f, 0.f, 0.f}, r21 = {xb[256 + u1], 0.f, 0.f, 0.f};
            f32x4 r30 = {xb[384 + u0], 0.f, 0.f, 0.f}, r31 = {xb[384 + u1], 0.f, 0.f, 0.f};
#pragma unroll
            for (int ks = 0; ks < 4; ++ks) {
                const f16x8 aa = *(const f16x8*)&hc[128 + kb + 32 * ks];
                r00 = MFMA16(aa, as_h8(wf[64 + 0 + ks]), r00);
                r01 = MFMA16(aa, as_h8(wf[64 + 4 + ks]), r01);
                r10 = MFMA16(aa, as_h8(wf[64 + 8 + ks]), r10);
                r11 = MFMA16(aa, as_h8(wf[64 + 12 + ks]), r11);
                r20 = MFMA16(aa, as_h8(wf[64 + 16 + ks]), r20);
                r21 = MFMA16(aa, as_h8(wf[64 + 20 + ks]), r21);
                r30 = MFMA16(aa, as_h8(wf[64 + 24 + ks]), r30);
                r31 = MFMA16(aa, as_h8(wf[64 + 28 + ks]), r31);
            }
            if (g16) {
                c1_0 = sigm(r10[0]) * c1_0 + sigm(r00[0]) * tanh_fast(r20[0]);
                const float h1n0 = sigm(r30[0]) * tanh_fast(c1_0);
                c1_1 = sigm(r11[0]) * c1_1 + sigm(r01[0]) * tanh_fast(r21[0]);
                const float h1n1 = sigm(r31[0]) * tanh_fast(c1_1);
                hn[128 + u0] = (_Float16)h1n0;
                hn[128 + u1] = (_Float16)h1n1;
            }
        }
        __syncthreads();
        cur ^= 1;
    }

    // ================= fused epilogue (R5/R6, strides 256) ===================
    {
        swl[T] = sub_W[T];
        const int uu = T & 127, half = T >> 7;
        const int sidx = subject_ids[b * 2 + half];
        const int slot = idxL[sidx];
        subj[T] = hl[slot * HPAD + uu];
    }
    __syncthreads();

    {
        const int uu = T & 127, half = T >> 7;
        const float* __restrict__ W = half ? gamma_W : beta_W;
        float acc = half ? gamma_b[uu] : beta_b[uu];
        for (int c = 0; c < 256; ++c) acc += subj[c] * W[c * 128 + uu];
        if (half) gm[uu] = acc;
        else      bt[uu] = acc;
    }
    __syncthreads();

    for (int i = T; i < 2560; i += 256) {
        const int o = i >> 7, c = i & 127;
        A[o][c] = gm[c] * po_W[c * 20 + o];
    }
    if (T < 20) {
        float k1 = po_b[T], k2 = 0.f;
        for (int c = 0; c < 128; ++c) {
            const float pw = po_W[c * 20 + T];
            k1 += bt[c] * pw;
            k2 += gm[c] * pw;
        }
        K1[T] = k1; K2[T] = k2;
    }
    const int nslot = (int)idxL[511] + 1;
    const float sb0 = sub_b[0], sb1 = sub_b[1];
    for (int s = T; s < nslot; s += 256) {
        const float4* hp4 = (const float4*)&hl[s * HPAD];
        float sum = 0.f, s2 = 0.f, sub0 = sb0, sub1 = sb1;
        for (int c4 = 0; c4 < 32; ++c4) {
            const float4 h = hp4[c4];
            sum += (h.x + h.y) + (h.z + h.w);
            s2  += h.x * h.x + h.y * h.y + h.z * h.z + h.w * h.w;
            const int c = 4 * c4;
            sub0 += h.x * swl[2 * c] + h.y * swl[2 * c + 2] + h.z * swl[2 * c + 4] + h.w * swl[2 * c + 6];
            sub1 += h.x * swl[2 * c + 1] + h.y * swl[2 * c + 3] + h.z * swl[2 * c + 5] + h.w * swl[2 * c + 7];
        }
        const float mu = sum * (1.f / 128.f);
        const float vv = fmaxf(s2 * (1.f / 128.f) - mu * mu, 0.f);
        urs[s][0] = mu;
        urs[s][1] = 1.f / sqrtf(vv + 1e-12f);
        subv[2 * s] = sub0; subv[2 * s + 1] = sub1;
    }
    __syncthreads();

    for (int i = T; i < nslot * 20; i += 256) {
        const int s = i / 20, o = i - 20 * s;
        const float mu = urs[s][0], rs = urs[s][1];
        const float4* hp4 = (const float4*)&hl[s * HPAD];
        const float* Ao = &A[o][0];
        float acc = 0.f;
        for (int c4 = 0; c4 < 32; ++c4) {
            const float4 h = hp4[c4];
            const float4 aa = *(const float4*)&Ao[4 * c4];
            acc += h.x * aa.x + h.y * aa.y + h.z * aa.z + h.w * aa.w;
        }
        povals[i] = rs * acc - mu * rs * K2[o] + K1[o];
    }
    __syncthreads();

    for (int i = T; i < 2560; i += 256) {
        const int t = i / 5, j = i - 5 * t;
        const int sl = idxL[t];
        const float4 v = *(const float4*)&povals[sl * 20 + 4 * j];
        *(float4*)&out[262144 + ((size_t)(b * 512 + t)) * 20 + 4 * j] = v;
    }
    for (int i = T; i < 512; i += 256) {
        const int sl = idxL[i];
        float2 v; v.x = subv[2 * sl]; v.y = subv[2 * sl + 1];
        *(float2*)&out[((size_t)(b * 512 + i)) * 2] = v;
    }
}

extern "C" void kernel_launch(void* const* d_in, const int* in_sizes, int n_in,
                              void* d_out, int out_size, void* d_ws, size_t ws_size,
                              hipStream_t stream) {
    (void)in_sizes; (void)n_in; (void)out_size; (void)ws_size;
    const int*   char_ids    = (const int*)d_in[0];
    const int*   word_ids    = (const int*)d_in[1];
    const int*   subject_ids = (const int*)d_in[2];
    const float* emb_char    = (const float*)d_in[3];
    const float* emb_word    = (const float*)d_in[4];
    const float* Wwc         = (const float*)d_in[5];
    const float* bwc         = (const float*)d_in[6];
    const float* l1_Wx       = (const float*)d_in[7];
    const float* l1_Wh       = (const float*)d_in[8];
    const float* l1_b        = (const float*)d_in[9];
    const float* l2_Wx       = (const float*)d_in[10];
    const float* l2_Wh       = (const float*)d_in[11];
    const float* l2_b        = (const float*)d_in[12];
    const float* beta_W      = (const float*)d_in[13];
    const float* beta_b      = (const float*)d_in[14];
    const float* gamma_W     = (const float*)d_in[15];
    const float* gamma_b     = (const float*)d_in[16];
    const float* sub_W       = (const float*)d_in[17];
    const float* sub_b       = (const float*)d_in[18];
    const float* po_W        = (const float*)d_in[19];
    const float* po_b        = (const float*)d_in[20];
    float* out = (float*)d_out;

    char* ws = (char*)d_ws;
    float* XW1 = (float*)(ws + 0);          // 20480 B (pad to 32768)
    uint4* WF  = (uint4*)(ws + 32768);      // 24576*16 = 393216 B -> ws 425984 B

    k_prep<<<dim3(58), dim3(512), 0, stream>>>(emb_char, emb_word, Wwc, bwc,
                                               l1_Wx, l1_b, l1_Wh, l2_Wx, l2_Wh,
                                               XW1, WF);
    k_lstm<<<dim3(256), dim3(256), 0, stream>>>(char_ids, word_ids, subject_ids,
                                                XW1, WF, l2_b,
                                                beta_W, beta_b, gamma_W, gamma_b,
                                                sub_W, sub_b, po_W, po_b, out);
}